// Round 1
// baseline (117528.809 us; speedup 1.0000x reference)
//
#include <hip/hip_runtime.h>

#define TT  512
#define BB  64
#define NII 1024
#define NHH 1024

__device__ __forceinline__ float sigmoidf_(float x) {
    return 1.0f / (1.0f + __expf(-x));
}

// One timestep. Grid: 256 blocks (each owns 4 hidden columns j0..j0+3 for all
// 64 batches, all 4 gates). Block: 512 threads = 8 K-slices (ky) x 64 batch
// lanes (m). Weight addresses are lane-invariant -> scalar loads; only the
// activation load (x or h_prev row) differs per lane.
__global__ __launch_bounds__(512, 1)
void lstm_step_kernel(const float* __restrict__ x_t,     // [BB][NII]
                      const float* __restrict__ h_prev,  // [BB][NHH]
                      float* __restrict__ h_out,         // [BB][NHH]
                      float* __restrict__ c_state,       // [BB][NHH]
                      const float* __restrict__ Wxf, const float* __restrict__ Whf, const float* __restrict__ bf,
                      const float* __restrict__ Wxi, const float* __restrict__ Whi, const float* __restrict__ bi,
                      const float* __restrict__ Wxc, const float* __restrict__ Whc, const float* __restrict__ bc,
                      const float* __restrict__ Wxo, const float* __restrict__ Who, const float* __restrict__ bo)
{
    __shared__ float red[8][64][16];   // 32 KB partials

    const int tid = threadIdx.x;
    const int ky  = tid >> 6;          // 0..7  (wave-uniform)
    const int m   = tid & 63;          // batch lane
    const int j0  = blockIdx.x * 4;    // 4 hidden columns per block

    const bool isx = (ky < 4);
    const int  k0  = (ky & 3) * 256;   // 256 K-elements per wave

    const float* __restrict__ A   = isx ? (x_t + (size_t)m * NII) : (h_prev + (size_t)m * NHH);
    const float* __restrict__ WfP = (isx ? Wxf : Whf) + j0;
    const float* __restrict__ WiP = (isx ? Wxi : Whi) + j0;
    const float* __restrict__ WcP = (isx ? Wxc : Whc) + j0;
    const float* __restrict__ WoP = (isx ? Wxo : Who) + j0;

    float4 accf = make_float4(0.f, 0.f, 0.f, 0.f);
    float4 acci = make_float4(0.f, 0.f, 0.f, 0.f);
    float4 accc = make_float4(0.f, 0.f, 0.f, 0.f);
    float4 acco = make_float4(0.f, 0.f, 0.f, 0.f);

    #pragma unroll 2
    for (int k = k0; k < k0 + 256; k += 4) {
        const float4 a4 = *reinterpret_cast<const float4*>(A + k);
        const float* ap = reinterpret_cast<const float*>(&a4);
        #pragma unroll
        for (int u = 0; u < 4; ++u) {
            const float  a   = ap[u];
            const size_t row = (size_t)(k + u) * NHH;
            const float4 wf  = *reinterpret_cast<const float4*>(WfP + row);
            const float4 wi  = *reinterpret_cast<const float4*>(WiP + row);
            const float4 wc  = *reinterpret_cast<const float4*>(WcP + row);
            const float4 wo  = *reinterpret_cast<const float4*>(WoP + row);
            accf.x = fmaf(a, wf.x, accf.x); accf.y = fmaf(a, wf.y, accf.y);
            accf.z = fmaf(a, wf.z, accf.z); accf.w = fmaf(a, wf.w, accf.w);
            acci.x = fmaf(a, wi.x, acci.x); acci.y = fmaf(a, wi.y, acci.y);
            acci.z = fmaf(a, wi.z, acci.z); acci.w = fmaf(a, wi.w, acci.w);
            accc.x = fmaf(a, wc.x, accc.x); accc.y = fmaf(a, wc.y, accc.y);
            accc.z = fmaf(a, wc.z, accc.z); accc.w = fmaf(a, wc.w, accc.w);
            acco.x = fmaf(a, wo.x, acco.x); acco.y = fmaf(a, wo.y, acco.y);
            acco.z = fmaf(a, wo.z, acco.z); acco.w = fmaf(a, wo.w, acco.w);
        }
    }

    // stash partials: red[ky][m][gate*4 + jl]
    {
        float* r = &red[ky][m][0];
        r[0]  = accf.x; r[1]  = accf.y; r[2]  = accf.z; r[3]  = accf.w;
        r[4]  = acci.x; r[5]  = acci.y; r[6]  = acci.z; r[7]  = acci.w;
        r[8]  = accc.x; r[9]  = accc.y; r[10] = accc.z; r[11] = accc.w;
        r[12] = acco.x; r[13] = acco.y; r[14] = acco.z; r[15] = acco.w;
    }
    __syncthreads();

    if (tid < 256) {
        const int mm = tid >> 2;
        const int jl = tid & 3;
        const int jc = j0 + jl;

        float g[4];
        #pragma unroll
        for (int gg = 0; gg < 4; ++gg) {
            float s = 0.f;
            #pragma unroll
            for (int q = 0; q < 8; ++q) s += red[q][mm][gg * 4 + jl];
            g[gg] = s;
        }
        const float F  = sigmoidf_(g[0] + bf[jc]);
        const float I  = sigmoidf_(g[1] + bi[jc]);
        const float Ct = tanhf(g[2] + bc[jc]);
        const float O  = sigmoidf_(g[3] + bo[jc]);

        const size_t idx = (size_t)mm * NHH + jc;
        const float cn = F * c_state[idx] + I * Ct;
        const float hn = O * tanhf(cn);
        c_state[idx] = cn;
        h_out[idx]   = hn;
    }
}

__global__ void finalize_kernel(const float* __restrict__ h_last,
                                const float* __restrict__ c_state,
                                float* __restrict__ tail)
{
    const int i = blockIdx.x * blockDim.x + threadIdx.x;
    if (i < BB * NHH) {
        tail[i]            = h_last[i];
        tail[BB * NHH + i] = c_state[i];
    }
}

extern "C" void kernel_launch(void* const* d_in, const int* in_sizes, int n_in,
                              void* d_out, int out_size, void* d_ws, size_t ws_size,
                              hipStream_t stream) {
    const float* inputs = (const float*)d_in[0];
    const float* Wxf = (const float*)d_in[1],  *Whf = (const float*)d_in[2],  *bf = (const float*)d_in[3];
    const float* Wxi = (const float*)d_in[4],  *Whi = (const float*)d_in[5],  *bi = (const float*)d_in[6];
    const float* Wxc = (const float*)d_in[7],  *Whc = (const float*)d_in[8],  *bc = (const float*)d_in[9];
    const float* Wxo = (const float*)d_in[10], *Who = (const float*)d_in[11], *bo = (const float*)d_in[12];

    float* out     = (float*)d_out;
    float* c_state = (float*)d_ws;            // [BB*NHH]
    float* h0      = c_state + BB * NHH;      // [BB*NHH] zeros

    hipMemsetAsync(d_ws, 0, (size_t)2 * BB * NHH * sizeof(float), stream);

    for (int t = 0; t < TT; ++t) {
        const float* hp = (t == 0) ? h0 : (out + (size_t)(t - 1) * BB * NHH);
        lstm_step_kernel<<<dim3(256), dim3(512), 0, stream>>>(
            inputs + (size_t)t * BB * NII, hp,
            out + (size_t)t * BB * NHH, c_state,
            Wxf, Whf, bf, Wxi, Whi, bi, Wxc, Whc, bc, Wxo, Who, bo);
    }

    finalize_kernel<<<dim3(256), dim3(256), 0, stream>>>(
        out + (size_t)(TT - 1) * BB * NHH, c_state, out + (size_t)TT * BB * NHH);
}

// Round 2
// 7566.605 us; speedup vs baseline: 15.5326x; 15.5326x over previous
//
#include <hip/hip_runtime.h>
#include <hip/hip_bf16.h>

#define TT  512
#define BB  64
#define NII 1024
#define NHH 1024

typedef __attribute__((ext_vector_type(8))) short bf16x8;
typedef __attribute__((ext_vector_type(4))) float f32x4;

__device__ __forceinline__ float sigmoidf_(float x) { return 1.0f / (1.0f + __expf(-x)); }

__device__ __forceinline__ short f2bf(float f) {
    __hip_bfloat16 h = __float2bfloat16(f);   // round-to-nearest-even
    union { __hip_bfloat16 b; short s; } u; u.b = h; return u.s;
}

// ---------------------------------------------------------------------------
// Pack all 8 weight matrices (fp32 [1024][1024] row-major, k x col) into
// MFMA-B-fragment-major bf16. Fused K = 2048 (x rows 0..1023, h rows 1024..2047).
// Block b owns cols j0=b*4..b*4+3 of each gate; fragment col n = gate*4 + jl.
// Layout: wpk[ ((b*64 + kk)*64 + l)*8 + e ]  holds  Wfused[kk*32 + (l>>4)*8 + e][n=l&15]
// ---------------------------------------------------------------------------
__global__ __launch_bounds__(256)
void pack_weights_kernel(const float* __restrict__ Wxf, const float* __restrict__ Whf,
                         const float* __restrict__ Wxi, const float* __restrict__ Whi,
                         const float* __restrict__ Wxc, const float* __restrict__ Whc,
                         const float* __restrict__ Wxo, const float* __restrict__ Who,
                         short* __restrict__ wpk)
{
    const int b = blockIdx.x;
    const int t = threadIdx.x;
    const float* Wx[4] = { Wxf, Wxi, Wxc, Wxo };
    const float* Wh[4] = { Whf, Whi, Whc, Who };

    for (int i = 0; i < 16; ++i) {
        const int pair = t + i * 256;        // 0..4095 = (kk, l)
        const int kk = pair >> 6;            // 0..63
        const int l  = pair & 63;
        const int n  = l & 15;
        const int g  = n >> 2;
        const int col = b * 4 + (n & 3);
        const int kf0 = kk * 32 + (l >> 4) * 8;   // 8-aligned, never crosses 1024
        const float* src = (kf0 < 1024) ? (Wx[g] + (size_t)kf0 * NHH + col)
                                        : (Wh[g] + (size_t)(kf0 - 1024) * NHH + col);
        short v[8];
        #pragma unroll
        for (int e = 0; e < 8; ++e) v[e] = f2bf(src[(size_t)e * NHH]);

        short* dst = wpk + ((size_t)(b * 64 + kk) * 64 + l) * 8;
        *reinterpret_cast<bf16x8*>(dst) = *reinterpret_cast<bf16x8*>(v);
    }
}

// ---------------------------------------------------------------------------
// One timestep. Grid 256 blocks x 512 threads (8 waves).
// Wave w: mi = w&3 (16-row batch tile), kh = w>>2 (K half: 0 = x part, 1 = h part).
// Each wave: 32 x mfma_f32_16x16x32_bf16 into one 16x16 f32 tile.
// A-frags: x read fp32 from global + cvt; h read from fragment-packed bf16 ping buf.
// B-frags: one coalesced 16B load from wpk.
// ---------------------------------------------------------------------------
__global__ __launch_bounds__(512, 1)
void lstm_step_kernel(const float* __restrict__ x_t,       // [BB][NII] fp32
                      const short* __restrict__ hpk_prev,  // packed bf16 A-frags [4][32][64][8]
                      const short* __restrict__ wpk,       // packed weights
                      float* __restrict__ h_out,           // [BB][NHH] fp32 (d_out slice)
                      short* __restrict__ hpk_next,        // packed bf16 A-frags
                      float* __restrict__ c_state,         // [BB][NHH] fp32
                      const float* __restrict__ bfv, const float* __restrict__ biv,
                      const float* __restrict__ bcv, const float* __restrict__ bov)
{
    __shared__ float red[4][64][4];      // partials from kh=1 waves (4 KB)
    __shared__ float gates[4][16][16];   // pre-activation gate values (4 KB... 16 KB)

    const int tid = threadIdx.x;
    const int w   = tid >> 6;
    const int l   = tid & 63;
    const int mi  = w & 3;
    const int kh  = w >> 2;
    const int b   = blockIdx.x;

    f32x4 acc0 = { 0.f, 0.f, 0.f, 0.f };
    f32x4 acc1 = { 0.f, 0.f, 0.f, 0.f };

    const short* bp = wpk + ((size_t)(b * 64 + kh * 32) * 64 + l) * 8;

    if (kh == 0) {
        // x half: fp32 loads + in-register bf16 convert
        const float* ap = x_t + (size_t)(mi * 16 + (l & 15)) * NII + (l >> 4) * 8;
        #pragma unroll 4
        for (int kk = 0; kk < 32; kk += 2) {
            f32x4 a0 = *reinterpret_cast<const f32x4*>(ap);
            f32x4 a1 = *reinterpret_cast<const f32x4*>(ap + 4);
            bf16x8 bfr0 = *reinterpret_cast<const bf16x8*>(bp);
            f32x4 a2 = *reinterpret_cast<const f32x4*>(ap + 32);
            f32x4 a3 = *reinterpret_cast<const f32x4*>(ap + 36);
            bf16x8 bfr1 = *reinterpret_cast<const bf16x8*>(bp + 512);
            bf16x8 afr0, afr1;
            afr0[0]=f2bf(a0[0]); afr0[1]=f2bf(a0[1]); afr0[2]=f2bf(a0[2]); afr0[3]=f2bf(a0[3]);
            afr0[4]=f2bf(a1[0]); afr0[5]=f2bf(a1[1]); afr0[6]=f2bf(a1[2]); afr0[7]=f2bf(a1[3]);
            afr1[0]=f2bf(a2[0]); afr1[1]=f2bf(a2[1]); afr1[2]=f2bf(a2[2]); afr1[3]=f2bf(a2[3]);
            afr1[4]=f2bf(a3[0]); afr1[5]=f2bf(a3[1]); afr1[6]=f2bf(a3[2]); afr1[7]=f2bf(a3[3]);
            acc0 = __builtin_amdgcn_mfma_f32_16x16x32_bf16(afr0, bfr0, acc0, 0, 0, 0);
            acc1 = __builtin_amdgcn_mfma_f32_16x16x32_bf16(afr1, bfr1, acc1, 0, 0, 0);
            ap += 64;
            bp += 1024;
        }
    } else {
        // h half: already packed bf16 fragments
        const short* ap = hpk_prev + ((size_t)(mi * 32) * 64 + l) * 8;
        #pragma unroll 4
        for (int kk = 0; kk < 32; kk += 2) {
            bf16x8 afr0 = *reinterpret_cast<const bf16x8*>(ap);
            bf16x8 bfr0 = *reinterpret_cast<const bf16x8*>(bp);
            bf16x8 afr1 = *reinterpret_cast<const bf16x8*>(ap + 512);
            bf16x8 bfr1 = *reinterpret_cast<const bf16x8*>(bp + 512);
            acc0 = __builtin_amdgcn_mfma_f32_16x16x32_bf16(afr0, bfr0, acc0, 0, 0, 0);
            acc1 = __builtin_amdgcn_mfma_f32_16x16x32_bf16(afr1, bfr1, acc1, 0, 0, 0);
            ap += 1024;
            bp += 1024;
        }
    }
    acc0[0] += acc1[0]; acc0[1] += acc1[1]; acc0[2] += acc1[2]; acc0[3] += acc1[3];

    if (kh == 1) {
        red[mi][l][0] = acc0[0]; red[mi][l][1] = acc0[1];
        red[mi][l][2] = acc0[2]; red[mi][l][3] = acc0[3];
    }
    __syncthreads();

    if (kh == 0) {
        // C/D layout: col = l&15, row = (l>>4)*4 + r
        #pragma unroll
        for (int r = 0; r < 4; ++r)
            gates[mi][(l >> 4) * 4 + r][l & 15] = acc0[r] + red[mi][l][r];
    }
    __syncthreads();

    if (tid < 256) {
        const int m  = tid >> 2;       // batch 0..63
        const int jl = tid & 3;
        const int mi2 = m >> 4, ml = m & 15;
        const int j  = b * 4 + jl;

        const float gf = gates[mi2][ml][0 * 4 + jl] + bfv[j];
        const float gi = gates[mi2][ml][1 * 4 + jl] + biv[j];
        const float gc = gates[mi2][ml][2 * 4 + jl] + bcv[j];
        const float go = gates[mi2][ml][3 * 4 + jl] + bov[j];

        const float F  = sigmoidf_(gf);
        const float I  = sigmoidf_(gi);
        const float Ct = tanhf(gc);
        const float O  = sigmoidf_(go);

        const size_t idx = (size_t)m * NHH + j;
        const float cn = F * c_state[idx] + I * Ct;
        const float hn = O * tanhf(cn);
        c_state[idx] = cn;
        h_out[idx]   = hn;

        // write packed bf16 H fragment element: H[m][k=j]
        const int kk2 = j >> 5;
        const int lg  = (j >> 3) & 3;
        const int e   = j & 7;
        hpk_next[((size_t)(mi2 * 32 + kk2) * 64 + (lg * 16 + ml)) * 8 + e] = f2bf(hn);
    }
}

__global__ void finalize_kernel(const float* __restrict__ h_last,
                                const float* __restrict__ c_state,
                                float* __restrict__ tail)
{
    const int i = blockIdx.x * blockDim.x + threadIdx.x;
    if (i < BB * NHH) {
        tail[i]            = h_last[i];
        tail[BB * NHH + i] = c_state[i];
    }
}

extern "C" void kernel_launch(void* const* d_in, const int* in_sizes, int n_in,
                              void* d_out, int out_size, void* d_ws, size_t ws_size,
                              hipStream_t stream) {
    const float* inputs = (const float*)d_in[0];
    const float* Wxf = (const float*)d_in[1],  *Whf = (const float*)d_in[2],  *bf = (const float*)d_in[3];
    const float* Wxi = (const float*)d_in[4],  *Whi = (const float*)d_in[5],  *bi = (const float*)d_in[6];
    const float* Wxc = (const float*)d_in[7],  *Whc = (const float*)d_in[8],  *bc = (const float*)d_in[9];
    const float* Wxo = (const float*)d_in[10], *Who = (const float*)d_in[11], *bo = (const float*)d_in[12];

    float* out = (float*)d_out;

    // ws layout: [wpk 16 MB][hpk0 128 KB][c_state 256 KB][hpk1 128 KB]
    char*  wsb   = (char*)d_ws;
    short* wpk   = (short*)wsb;
    short* hpk0  = (short*)(wsb + (size_t)16 * 1024 * 1024);
    float* c_st  = (float*)(wsb + (size_t)16 * 1024 * 1024 + 128 * 1024);
    short* hpk1  = (short*)(wsb + (size_t)16 * 1024 * 1024 + 128 * 1024 + 256 * 1024);
    short* hpk[2] = { hpk0, hpk1 };

    // zero hpk0 + c_state (contiguous 384 KB)
    hipMemsetAsync(hpk0, 0, 384 * 1024, stream);

    pack_weights_kernel<<<dim3(256), dim3(256), 0, stream>>>(
        Wxf, Whf, Wxi, Whi, Wxc, Whc, Wxo, Who, wpk);

    for (int t = 0; t < TT; ++t) {
        lstm_step_kernel<<<dim3(256), dim3(512), 0, stream>>>(
            inputs + (size_t)t * BB * NII,
            hpk[t & 1], wpk,
            out + (size_t)t * BB * NHH,
            hpk[(t + 1) & 1],
            c_st,
            bf, bi, bc, bo);
    }

    finalize_kernel<<<dim3(256), dim3(256), 0, stream>>>(
        out + (size_t)(TT - 1) * BB * NHH, c_st, out + (size_t)TT * BB * NHH);
}